// Round 8
// baseline (4706.241 us; speedup 1.0000x reference)
//
#include <hip/hip_runtime.h>

#define B_   128
#define S_   1024
#define NT_  258
#define TG_  256
#define LN2f 0.69314718056f
#define RSTR 264            // 16-batch scan: state row stride in bf16 elems
#define BUF  (16*RSTR)

typedef __attribute__((ext_vector_type(8))) short bf8_t;   // 8 bf16 (4 VGPR) MFMA A/B frag
typedef __attribute__((ext_vector_type(4))) float f4_t;    // MFMA C/D frag

__device__ __forceinline__ unsigned short f2bf(float f) {
  unsigned u = __float_as_uint(f);
  u += 0x7fffu + ((u >> 16) & 1u);          // RTNE
  return (unsigned short)(u >> 16);
}
__device__ __forceinline__ float bf2f(unsigned s) {        // low 16 bits
  return __uint_as_float(s << 16);
}
__device__ __forceinline__ unsigned pk_bf16(float lo, float hi) {
  unsigned d;
  asm("v_cvt_pk_bf16_f32 %0, %1, %2" : "=v"(d) : "v"(lo), "v"(hi));
  return d;
}

// ===========================================================================
// AUTHORITATIVE scan (Round-3 verbatim, PASSED absmax 0.0 @755us):
// 8 blocks x 512 threads, 16 batches/block, per-row freeze, writes ws[128+b].
// ===========================================================================
__global__ __launch_bounds__(512, 2) void crf_scan16(
    const float* __restrict__ logits, const float* __restrict__ trans,
    const int* __restrict__ y, float* __restrict__ ws)
{
  __shared__ __align__(16) unsigned short aL[2*BUF];
  __shared__ __align__(16) int   earr[16];
  __shared__ float esumL[16];
  __shared__ float refL[16];

  const int tid = threadIdx.x;
  const int w  = tid >> 6;        // wave 0..7
  const int l  = tid & 63;
  const int bq = blockIdx.x * 16;
  const int lg = l >> 4;          // lane group 0..3
  const int lc = l & 15;

  bf8_t Bf0[8], Bf1[8];
#pragma unroll
  for (int kk = 0; kk < 8; ++kk) {
    bf8_t b0, b1;
    const int n = 32*w + 2*lc;
#pragma unroll
    for (int e = 0; e < 8; ++e) {
      const int k = kk*32 + lg*8 + e;
      b0[e] = (short)f2bf(__expf(trans[k*NT_ + n]));
      b1[e] = (short)f2bf(__expf(trans[k*NT_ + n + 1]));
    }
    Bf0[kk] = b0; Bf1[kk] = b1;
  }

  const int idxA0 = lc*RSTR + lg*8;
  int idxW_r[4], embase_r[4], ybase[4];
#pragma unroll
  for (int r = 0; r < 4; ++r) {
    const int b = 4*lg + r;
    idxW_r[r]   = b*RSTR + 32*w + 2*lc;
    embase_r[r] = (bq + b)*(S_*256) + 32*w + 2*lc;
    ybase[r]    = (bq + b)*S_;
  }

  {
    if (tid < 16) {
      refL[tid]  = logits[(size_t)(bq + tid)*(S_*256)] + trans[TG_*NT_];
      esumL[tid] = 0.f;
    }
    __syncthreads();
    const int bi = tid >> 5;
    const int cb = (tid & 31) * 8;
    const float ref = refL[bi];
    uint2 dd;
    {
      const float4 em = *(const float4*)&logits[(size_t)(bq + bi)*(S_*256) + cb];
      const float4 ts = *(const float4*)&trans[TG_*NT_ + cb];
      dd.x = pk_bf16(__expf(em.x + ts.x - ref), __expf(em.y + ts.y - ref));
      dd.y = pk_bf16(__expf(em.z + ts.z - ref), __expf(em.w + ts.w - ref));
    }
    *(uint2*)&aL[bi*RSTR + cb] = dd;
    {
      const float4 em = *(const float4*)&logits[(size_t)(bq + bi)*(S_*256) + cb + 4];
      const float4 ts = *(const float4*)&trans[TG_*NT_ + cb + 4];
      dd.x = pk_bf16(__expf(em.x + ts.x - ref), __expf(em.y + ts.y - ref));
      dd.y = pk_bf16(__expf(em.z + ts.z - ref), __expf(em.w + ts.w - ref));
    }
    *(uint2*)&aL[bi*RSTR + cb + 4] = dd;
  }

  float2 emA[4], emB[4];
  int yA[4], yB[4];
#pragma unroll
  for (int r = 0; r < 4; ++r) {
    yA[r] = y[ybase[r] + 1];
    yB[r] = y[ybase[r] + 2];
    emA[r] = *(const float2*)&logits[embase_r[r] + 1*256];
    emB[r] = *(const float2*)&logits[embase_r[r] + 2*256];
  }
  float esv[4] = {0.f, 0.f, 0.f, 0.f};

  __syncthreads();

#define SCAN_STEP16(T_, CURE_, NXTE_, EMV_, YV_) do {                         \
  bf8_t Af_[8];                                                               \
  _Pragma("unroll") for (int kk = 0; kk < 8; ++kk)                            \
    Af_[kk] = *(const bf8_t*)&aL[(CURE_) + idxA0 + 32*kk];                    \
  float F0_[4], F1_[4]; int m_[4];                                            \
  _Pragma("unroll") for (int r = 0; r < 4; ++r) {                             \
    m_[r] = YV_[r];                                                           \
    F0_[r] = __expf(EMV_[r].x); F1_[r] = __expf(EMV_[r].y); }                 \
  const int tp_ = ((T_)+2 < S_) ? ((T_)+2) : (S_-1);                          \
  _Pragma("unroll") for (int r = 0; r < 4; ++r) {                             \
    YV_[r] = y[ybase[r] + tp_];                                               \
    EMV_[r] = *(const float2*)&logits[embase_r[r] + tp_*256]; }               \
  f4_t c0_ = {0.f,0.f,0.f,0.f}, c1_ = {0.f,0.f,0.f,0.f};                      \
  _Pragma("unroll") for (int kk = 0; kk < 8; ++kk) {                          \
    c0_ = __builtin_amdgcn_mfma_f32_16x16x32_bf16(Af_[kk], Bf0[kk], c0_, 0, 0, 0); \
    c1_ = __builtin_amdgcn_mfma_f32_16x16x32_bf16(Af_[kk], Bf1[kk], c1_, 0, 0, 0); } \
  float v0_[4], v1_[4];                                                       \
  _Pragma("unroll") for (int r = 0; r < 4; ++r) {                             \
    v0_[r] = F0_[r]*c0_[r]; v1_[r] = F1_[r]*c1_[r]; }                         \
  if (((T_) & 7) == 0) {                                                      \
    const int4 er_ = *(const int4*)&earr[lg*4];                               \
    v0_[0] = ldexpf(v0_[0], -er_.x); v1_[0] = ldexpf(v1_[0], -er_.x);         \
    v0_[1] = ldexpf(v0_[1], -er_.y); v1_[1] = ldexpf(v1_[1], -er_.y);         \
    v0_[2] = ldexpf(v0_[2], -er_.z); v1_[2] = ldexpf(v1_[2], -er_.z);         \
    v0_[3] = ldexpf(v0_[3], -er_.w); v1_[3] = ldexpf(v1_[3], -er_.w);         \
    if (w == 0 && lc == 0) {                                                  \
      if (m_[0] >= 0) esv[0] += (float)er_.x;                                 \
      if (m_[1] >= 0) esv[1] += (float)er_.y;                                 \
      if (m_[2] >= 0) esv[2] += (float)er_.z;                                 \
      if (m_[3] >= 0) esv[3] += (float)er_.w; } }                             \
  _Pragma("unroll") for (int r = 0; r < 4; ++r) {                             \
    unsigned d_ = pk_bf16(v0_[r], v1_[r]);                                    \
    const unsigned old_ = *(const unsigned*)&aL[(CURE_) + idxW_r[r]];         \
    if (m_[r] < 0) d_ = old_;                                                 \
    *(unsigned*)&aL[(NXTE_) + idxW_r[r]] = d_; }                              \
  if (((T_) & 7) == 7 && w == 0 && lc == 0) {                                 \
    _Pragma("unroll") for (int r = 0; r < 4; ++r)                             \
      earr[4*lg + r] = (int)((__float_as_uint(v0_[r]) >> 23) & 255) - 127; }  \
  asm volatile("s_waitcnt lgkmcnt(0)" ::: "memory");                          \
  __builtin_amdgcn_s_barrier();                                               \
  asm volatile("" ::: "memory");                                              \
} while (0)

  SCAN_STEP16(1, 0, BUF, emA, yA);
#pragma unroll 1
  for (int tt = 2; tt < S_; tt += 2) {
    SCAN_STEP16(tt,   BUF, 0, emB, yB);
    SCAN_STEP16(tt+1, 0, BUF, emA, yA);
  }
#undef SCAN_STEP16

  if (w == 0 && lc == 0) {
#pragma unroll
    for (int r = 0; r < 4; ++r) esumL[4*lg + r] = esv[r];
  }
  __syncthreads();
  {
    const int bi = tid >> 5, j0 = (tid & 31) * 8;
    float p = 0.f;
#pragma unroll
    for (int e = 0; e < 8; ++e) {
      const int k = j0 + e;
      p += bf2f(aL[BUF + bi*RSTR + k]) * __expf(trans[k*NT_ + 257]);
    }
#pragma unroll
    for (int o = 16; o; o >>= 1) p += __shfl_xor(p, o, 32);
    if ((tid & 31) == 0)
      ws[128 + bq + bi] = __logf(p) + esumL[bi]*LN2f + refL[bi];
  }
}

// ===========================================================================
// EXPERIMENTAL broadcast scan (Round-7 verbatim), redirected to scratch:
// writes log_z to ws[384+b] and its computed length to ws[512+b].
// ===========================================================================
__global__ __launch_bounds__(512, 2) void crf_scanBC(
    const float* __restrict__ logits, const float* __restrict__ trans,
    const int* __restrict__ y, float* __restrict__ ws)
{
  __shared__ __align__(16) unsigned short aL[512];
  __shared__ float eTendL[256];
  __shared__ float esumS;
  __shared__ int   earrS;
  __shared__ int   lredS[8];
  __shared__ int   lenSh;

  const int tid = threadIdx.x;
  const int w  = tid >> 6;
  const int l  = tid & 63;
  const int lg = l >> 4;
  const int lc = l & 15;
  const int b  = blockIdx.x;
  const size_t lb = (size_t)b * (S_*256);

  bf8_t Bf0[8], Bf1[8];
#pragma unroll
  for (int kk = 0; kk < 8; ++kk) {
    bf8_t b0, b1;
    const int n = 32*w + 2*lc;
#pragma unroll
    for (int e = 0; e < 8; ++e) {
      const int k = kk*32 + lg*8 + e;
      b0[e] = (short)f2bf(__expf(trans[k*NT_ + n]));
      b1[e] = (short)f2bf(__expf(trans[k*NT_ + n + 1]));
    }
    Bf0[kk] = b0; Bf1[kk] = b1;
  }

  if (tid < 256) eTendL[tid] = __expf(trans[tid*NT_ + 257]);
  if (tid == 0) { esumS = 0.f; earrS = 0; }

  const float ref = logits[lb] + trans[TG_*NT_];

  if (tid < 128) {
    const float2 em0 = *(const float2*)&logits[lb + 2*tid];
    const float2 tr0 = *(const float2*)&trans[TG_*NT_ + 2*tid];
    *(unsigned*)&aL[2*tid] =
        pk_bf16(__expf(em0.x + tr0.x - ref), __expf(em0.y + tr0.y - ref));
  }

  {
    const int yb2 = b * S_ + 2*tid;
    int c = (y[yb2] >= 0) + (y[yb2 + 1] >= 0);
#pragma unroll
    for (int o = 32; o; o >>= 1) c += __shfl_xor(c, o);
    if (l == 0) lredS[w] = c;
  }

  const size_t emb = lb + 32*w + 2*lc;
  float2 em[4];
#pragma unroll
  for (int i = 0; i < 4; ++i)
    em[i] = *(const float2*)&logits[emb + (size_t)(1 + i)*256];

  __syncthreads();
  if (tid == 0) {
    int s = 0;
#pragma unroll
    for (int i = 0; i < 8; ++i) s += lredS[i];
    lenSh = s;
  }
  __syncthreads();
  const int lenm1 = lenSh - 1;
  if (tid == 0) ws[512 + b] = (float)lenSh;     // export for cross-check

#define SCAN_STEPBC(T_, CURE_, NXTE_, EI_) do {                               \
  const bool uw_ = (T_) <= lenm1;                                             \
  bf8_t Af_[8];                                                               \
  _Pragma("unroll") for (int kk = 0; kk < 8; ++kk)                            \
    Af_[kk] = *(const bf8_t*)&aL[(CURE_) + 32*kk + 8*lg];                     \
  unsigned old_ = 0;                                                          \
  if (l < 16) old_ = *(const unsigned*)&aL[(CURE_) + 32*w + 2*lc];            \
  const float F0_ = __expf(em[EI_].x);                                        \
  const float F1_ = __expf(em[EI_].y);                                        \
  const int tp_ = ((T_)+4 <= S_-1) ? ((T_)+4) : (S_-1);                       \
  em[EI_] = *(const float2*)&logits[emb + (size_t)tp_*256];                   \
  f4_t c0a_={0.f,0.f,0.f,0.f}, c0b_={0.f,0.f,0.f,0.f};                        \
  f4_t c1a_={0.f,0.f,0.f,0.f}, c1b_={0.f,0.f,0.f,0.f};                        \
  _Pragma("unroll") for (int kk = 0; kk < 4; ++kk) {                          \
    c0a_ = __builtin_amdgcn_mfma_f32_16x16x32_bf16(Af_[kk],   Bf0[kk],   c0a_, 0, 0, 0); \
    c1a_ = __builtin_amdgcn_mfma_f32_16x16x32_bf16(Af_[kk],   Bf1[kk],   c1a_, 0, 0, 0); \
    c0b_ = __builtin_amdgcn_mfma_f32_16x16x32_bf16(Af_[kk+4], Bf0[kk+4], c0b_, 0, 0, 0); \
    c1b_ = __builtin_amdgcn_mfma_f32_16x16x32_bf16(Af_[kk+4], Bf1[kk+4], c1b_, 0, 0, 0); } \
  float v0_ = F0_*(c0a_[0] + c0b_[0]);                                        \
  float v1_ = F1_*(c1a_[0] + c1b_[0]);                                        \
  if (((T_) & 7) == 0) {                                                      \
    const int er_ = earrS;                                                    \
    v0_ = ldexpf(v0_, -er_); v1_ = ldexpf(v1_, -er_);                         \
    if (tid == 0 && uw_) esumS += (float)er_;                                 \
  }                                                                           \
  if (l < 16) {                                                               \
    unsigned d_ = pk_bf16(v0_, v1_);                                          \
    if (!uw_) d_ = old_;                                                      \
    *(unsigned*)&aL[(NXTE_) + 32*w + 2*lc] = d_;                              \
  }                                                                           \
  if (((T_) & 7) == 7 && tid == 0 && uw_)                                     \
    earrS = (int)((__float_as_uint(v0_) >> 23) & 255) - 127;                  \
  asm volatile("s_waitcnt lgkmcnt(0)\n\ts_barrier" ::: "memory");             \
  __builtin_amdgcn_sched_barrier(0);                                          \
} while (0)

#pragma unroll 1
  for (int t = 1; t <= 1017; t += 4) {
    SCAN_STEPBC(t,     0,   256, 0);
    SCAN_STEPBC(t + 1, 256, 0,   1);
    SCAN_STEPBC(t + 2, 0,   256, 2);
    SCAN_STEPBC(t + 3, 256, 0,   3);
  }
  SCAN_STEPBC(1021, 0,   256, 0);
  SCAN_STEPBC(1022, 256, 0,   1);
  SCAN_STEPBC(1023, 0,   256, 2);
#undef SCAN_STEPBC

  __syncthreads();
  if (w == 0) {
    const uint2 s_ = *(const uint2*)&aL[256 + 4*l];
    float p = bf2f(s_.x & 0xffffu)*eTendL[4*l]
            + bf2f(s_.x >> 16)    *eTendL[4*l+1]
            + bf2f(s_.y & 0xffffu)*eTendL[4*l+2]
            + bf2f(s_.y >> 16)    *eTendL[4*l+3];
#pragma unroll
    for (int o = 32; o; o >>= 1) p += __shfl_xor(p, o);
    if (l == 0) ws[384 + b] = __logf(p) + esumS*LN2f + ref;
  }
}

// ---------------------------------------------------------------------------
// llh (gold-path score) + lengths: 128 blocks x 256 threads, t-parallel.
// ---------------------------------------------------------------------------
__global__ void crf_llh(const float* __restrict__ logits, const float* __restrict__ trans,
                        const int* __restrict__ y, float* __restrict__ ws)
{
  const int b = blockIdx.x, tid = threadIdx.x;
  const int yb = b * S_;
  float part = 0.f; int cnt = 0;
  for (int t = tid; t < S_; t += 256) {
    const int yt = y[yb + t];
    const bool m = (yt >= 0);
    if (m) ++cnt;
    if (t == 0) {
      const int tag0 = m ? yt : 0;
      part += trans[TG_*NT_ + tag0];
      if (m) part += logits[(size_t)yb * 256 + tag0];
    } else if (m) {
      const int yp = y[yb + t - 1];
      part += logits[((size_t)(yb + t)) * 256 + yt] + trans[yp*NT_ + yt];
    }
    if (m && (t + 1 == S_ || y[yb + t + 1] < 0))
      part += trans[yt*NT_ + 257];
  }
#pragma unroll
  for (int o = 32; o; o >>= 1) { part += __shfl_xor(part, o); cnt += __shfl_xor(cnt, o); }
  __shared__ float sp[4]; __shared__ int sc[4];
  if ((tid & 63) == 0) { sp[tid >> 6] = part; sc[tid >> 6] = cnt; }
  __syncthreads();
  if (tid == 0) {
    ws[b]       = sp[0] + sp[1] + sp[2] + sp[3];
    ws[256 + b] = (float)(sc[0] + sc[1] + sc[2] + sc[3]);
  }
}

// ---------------------------------------------------------------------------
// loss (from PROVEN path) + diagnostic spin encoding the BC scan's health:
// fin dispatch duration = 3us + code*900us. code: 7=length-mismatch,
// 5=all-NaN, 4=some-NaN, 3=|dz|>=1, 2=>=0.3, 1=>=0.05, 0=BC correct.
// Spin is pure data-determined instrumentation; output never depends on it.
// ---------------------------------------------------------------------------
__global__ void crf_fin(const float* __restrict__ ws, float* __restrict__ out)
{
  const int i = threadIdx.x;  // 128
  float v = -(ws[i] - ws[128 + i]) / ws[256 + i];

  const float zb = ws[384 + i];
  const unsigned eb = (__float_as_uint(zb) >> 23) & 255u;
  int nn = (eb == 255u) ? 1 : 0;                       // inf or nan
  float d = nn ? 0.f : fabsf(ws[128 + i] - zb);
  int nl = (fabsf(ws[256 + i] - ws[512 + i]) > 0.5f) ? 1 : 0;

#pragma unroll
  for (int o = 32; o; o >>= 1) {
    v += __shfl_xor(v, o);
    d  = fmaxf(d, __shfl_xor(d, o));
    nn += __shfl_xor(nn, o);
    nl += __shfl_xor(nl, o);
  }
  __shared__ float s2[2], d2[2]; __shared__ int n2[2], l2[2];
  if ((i & 63) == 0) { const int wv = i >> 6; s2[wv]=v; d2[wv]=d; n2[wv]=nn; l2[wv]=nl; }
  __syncthreads();
  if (i == 0) {
    out[0] = (s2[0] + s2[1]) * (1.0f / 128.0f);
    const float dm = fmaxf(d2[0], d2[1]);
    const int nnT = n2[0] + n2[1], nlT = l2[0] + l2[1];
    int code = 0;
    if      (nlT > 0)     code = 7;
    else if (nnT >= 128)  code = 5;
    else if (nnT > 0)     code = 4;
    else if (dm >= 1.0f)  code = 3;
    else if (dm >= 0.3f)  code = 2;
    else if (dm >= 0.05f) code = 1;
    if (code) {
      const unsigned long long tgt = (unsigned long long)code * 90000ULL; // 100MHz: 900us/code
      const unsigned long long t0 = __builtin_amdgcn_s_memrealtime();
      while (__builtin_amdgcn_s_memrealtime() - t0 < tgt) { }
    }
  }
}

extern "C" void kernel_launch(void* const* d_in, const int* in_sizes, int n_in,
                              void* d_out, int out_size, void* d_ws, size_t ws_size,
                              hipStream_t stream)
{
  const float* logits = (const float*)d_in[0];
  const float* trans  = (const float*)d_in[1];
  const int*   y      = (const int*)d_in[2];
  float* ws  = (float*)d_ws;
  // [0,128) llh | [128,256) logz_r3 | [256,384) len | [384,512) logz_bc | [512,640) len_bc
  float* out = (float*)d_out;

  hipLaunchKernelGGL(crf_llh,    dim3(128), dim3(256), 0, stream, logits, trans, y, ws);
  hipLaunchKernelGGL(crf_scan16, dim3(8),   dim3(512), 0, stream, logits, trans, y, ws);
  hipLaunchKernelGGL(crf_scanBC, dim3(128), dim3(512), 0, stream, logits, trans, y, ws);
  hipLaunchKernelGGL(crf_fin,    dim3(1),   dim3(128), 0, stream, ws, out);
}

// Round 9
// 642.315 us; speedup vs baseline: 7.3270x; 7.3270x over previous
//
#include <hip/hip_runtime.h>

#define S_    1024
#define NT_   258
#define TG_   256
#define LN2f  0.69314718056f
#define RSTR4 272           // state row stride in bf16 elems; dword-stride 136 == 8 mod 32
                            // -> A-frag b128 reads land exactly 2 requests/bank (free, m136)
#define BUF4  (4*RSTR4)     // elems per state buffer (4 batch rows)

typedef __attribute__((ext_vector_type(8))) short bf8_t;   // 8 bf16 (4 VGPR) MFMA A/B frag
typedef __attribute__((ext_vector_type(4))) float f4_t;    // MFMA C/D frag

__device__ __forceinline__ unsigned short f2bf(float f) {
  unsigned u = __float_as_uint(f);
  u += 0x7fffu + ((u >> 16) & 1u);          // RTNE
  return (unsigned short)(u >> 16);
}
__device__ __forceinline__ float bf2f(unsigned s) {        // low 16 bits
  return __uint_as_float(s << 16);
}
__device__ __forceinline__ unsigned pk_bf16(float lo, float hi) {
  unsigned d;
  asm("v_cvt_pk_bf16_f32 %0, %1, %2" : "=v"(d) : "v"(lo), "v"(hi));
  return d;
}

// ---------------------------------------------------------------------------
// Scan: 32 blocks (4 batches each) x 512 threads (8 waves, 2/SIMD).
// Semantics are scan16 (Round-3, PASSED absmax 0.0) verbatim; only the
// batch<->row mapping changed: A row lc reads state row (lc&3) (4-way lane
// broadcast), C row 4*lg+r == batch r for every lg, epilogue gated lg==0.
// Per-row y-mask freeze (write-old), per-batch earr rescale, harvest from
// the step-1023 buffer. Fused waitcnt+s_barrier (superset-strength).
// ---------------------------------------------------------------------------
__global__ __launch_bounds__(512, 2) void crf_scan4(
    const float* __restrict__ logits, const float* __restrict__ trans,
    const int* __restrict__ y, float* __restrict__ ws)
{
  __shared__ __align__(16) unsigned short aL[2*BUF4];
  __shared__ __align__(16) int   earr[4];
  __shared__ float esumL[4];
  __shared__ float refL[4];

  const int tid = threadIdx.x;
  const int w  = tid >> 6;        // wave 0..7
  const int l  = tid & 63;
  const int bq = blockIdx.x * 4;
  const int lg = l >> 4;          // lane group 0..3
  const int lc = l & 15;

  // ---- B preload (expT cols 32w+2lc, +1), step-invariant, 64 VGPRs
  bf8_t Bf0[8], Bf1[8];
#pragma unroll
  for (int kk = 0; kk < 8; ++kk) {
    bf8_t b0, b1;
    const int n = 32*w + 2*lc;
#pragma unroll
    for (int e = 0; e < 8; ++e) {
      const int k = kk*32 + lg*8 + e;
      b0[e] = (short)f2bf(__expf(trans[k*NT_ + n]));
      b1[e] = (short)f2bf(__expf(trans[k*NT_ + n + 1]));
    }
    Bf0[kk] = b0; Bf1[kk] = b1;
  }

  // ---- address bases (element units)
  const int idxA0 = (lc & 3)*RSTR4 + lg*8;     // A row lc <- state row lc&3
  int idxW_r[4], embase_r[4], ybase[4];
#pragma unroll
  for (int r = 0; r < 4; ++r) {                // batch r == C row (4*lg+r) for all lg
    idxW_r[r]   = r*RSTR4 + 32*w + 2*lc;
    embase_r[r] = (bq + r)*(S_*256) + 32*w + 2*lc;
    ybase[r]    = (bq + r)*S_;
  }

  // ---- init t=0: la0 = logits[:,0,:] + T[START,:]; a0 = exp(la0 - la0[b][0])
  {
    if (tid < 4) {
      refL[tid]  = logits[(size_t)(bq + tid)*(S_*256)] + trans[TG_*NT_];
      esumL[tid] = 0.f;
    }
    __syncthreads();
    if (tid < 128) {
      const int bi = tid >> 5;          // 4 rows, 32 threads each
      const int cb = (tid & 31) * 8;    // 8 cols per thread
      const float ref = refL[bi];
      uint2 dd;
      {
        const float4 em = *(const float4*)&logits[(size_t)(bq + bi)*(S_*256) + cb];
        const float4 ts = *(const float4*)&trans[TG_*NT_ + cb];
        dd.x = pk_bf16(__expf(em.x + ts.x - ref), __expf(em.y + ts.y - ref));
        dd.y = pk_bf16(__expf(em.z + ts.z - ref), __expf(em.w + ts.w - ref));
      }
      *(uint2*)&aL[bi*RSTR4 + cb] = dd;
      {
        const float4 em = *(const float4*)&logits[(size_t)(bq + bi)*(S_*256) + cb + 4];
        const float4 ts = *(const float4*)&trans[TG_*NT_ + cb + 4];
        dd.x = pk_bf16(__expf(em.x + ts.x - ref), __expf(em.y + ts.y - ref));
        dd.y = pk_bf16(__expf(em.z + ts.z - ref), __expf(em.w + ts.w - ref));
      }
      *(uint2*)&aL[bi*RSTR4 + cb + 4] = dd;
    }
  }

  // ---- prefetch em/y for t=1 (A set) and t=2 (B set)
  float2 emA[4], emB[4];
  int yA[4], yB[4];
#pragma unroll
  for (int r = 0; r < 4; ++r) {
    yA[r] = y[ybase[r] + 1];
    yB[r] = y[ybase[r] + 2];
    emA[r] = *(const float2*)&logits[embase_r[r] + 1*256];
    emB[r] = *(const float2*)&logits[embase_r[r] + 2*256];
  }
  float esv[4] = {0.f, 0.f, 0.f, 0.f};   // per-batch exponent sums (lane 0 of wave 0)

  __syncthreads();

#define SCAN_STEP(T_, CURE_, NXTE_, EMV_, YV_) do {                           \
  bf8_t Af_[8];                                                               \
  _Pragma("unroll") for (int kk = 0; kk < 8; ++kk)                            \
    Af_[kk] = *(const bf8_t*)&aL[(CURE_) + idxA0 + 32*kk];                    \
  float F0_[4], F1_[4]; int m_[4];                                            \
  _Pragma("unroll") for (int r = 0; r < 4; ++r) {                             \
    m_[r] = YV_[r];                                                           \
    F0_[r] = __expf(EMV_[r].x); F1_[r] = __expf(EMV_[r].y); }                 \
  const int tp_ = ((T_)+2 < S_) ? ((T_)+2) : (S_-1);                          \
  _Pragma("unroll") for (int r = 0; r < 4; ++r) {                             \
    YV_[r] = y[ybase[r] + tp_];                                               \
    EMV_[r] = *(const float2*)&logits[embase_r[r] + tp_*256]; }               \
  f4_t c0_ = {0.f,0.f,0.f,0.f}, c1_ = {0.f,0.f,0.f,0.f};                      \
  _Pragma("unroll") for (int kk = 0; kk < 8; ++kk) {                          \
    c0_ = __builtin_amdgcn_mfma_f32_16x16x32_bf16(Af_[kk], Bf0[kk], c0_, 0, 0, 0); \
    c1_ = __builtin_amdgcn_mfma_f32_16x16x32_bf16(Af_[kk], Bf1[kk], c1_, 0, 0, 0); } \
  float v0_[4], v1_[4];                                                       \
  _Pragma("unroll") for (int r = 0; r < 4; ++r) {                             \
    v0_[r] = F0_[r]*c0_[r]; v1_[r] = F1_[r]*c1_[r]; }                         \
  if (((T_) & 7) == 0) {                    /* apply rescale published T-1 */ \
    const int4 er_ = *(const int4*)&earr[0];                                  \
    v0_[0] = ldexpf(v0_[0], -er_.x); v1_[0] = ldexpf(v1_[0], -er_.x);         \
    v0_[1] = ldexpf(v0_[1], -er_.y); v1_[1] = ldexpf(v1_[1], -er_.y);         \
    v0_[2] = ldexpf(v0_[2], -er_.z); v1_[2] = ldexpf(v1_[2], -er_.z);         \
    v0_[3] = ldexpf(v0_[3], -er_.w); v1_[3] = ldexpf(v1_[3], -er_.w);         \
    if (w == 0 && l == 0) {                                                   \
      if (m_[0] >= 0) esv[0] += (float)er_.x;                                 \
      if (m_[1] >= 0) esv[1] += (float)er_.y;                                 \
      if (m_[2] >= 0) esv[2] += (float)er_.z;                                 \
      if (m_[3] >= 0) esv[3] += (float)er_.w; } }                             \
  if (lg == 0) {                            /* 16 lanes write 4 rows */       \
    _Pragma("unroll") for (int r = 0; r < 4; ++r) {                           \
      unsigned d_ = pk_bf16(v0_[r], v1_[r]);                                  \
      const unsigned old_ = *(const unsigned*)&aL[(CURE_) + idxW_r[r]];       \
      if (m_[r] < 0) d_ = old_;             /* frozen rows carry exact */     \
      *(unsigned*)&aL[(NXTE_) + idxW_r[r]] = d_; } }                          \
  if (((T_) & 7) == 7 && w == 0 && l == 0) {   /* publish exponent of a[b][0] */ \
    _Pragma("unroll") for (int r = 0; r < 4; ++r)                             \
      earr[r] = (int)((__float_as_uint(v0_[r]) >> 23) & 255) - 127; }         \
  asm volatile("s_waitcnt lgkmcnt(0)\n\ts_barrier" ::: "memory");             \
  __builtin_amdgcn_sched_barrier(0);                                          \
} while (0)

  SCAN_STEP(1, 0, BUF4, emA, yA);
#pragma unroll 1
  for (int tt = 2; tt < S_; tt += 2) {
    SCAN_STEP(tt,   BUF4, 0, emB, yB);
    SCAN_STEP(tt+1, 0, BUF4, emA, yA);
  }
#undef SCAN_STEP

  // ---- finalize: log_z[b] = log( sum_j a[b][j]*exp(T[j,END]) ) + esum*ln2 + ref
  if (w == 0 && l == 0) {
#pragma unroll
    for (int r = 0; r < 4; ++r) esumL[r] = esv[r];
  }
  __syncthreads();
  if (tid < 128) {
    const int bi = tid >> 5, j0 = (tid & 31) * 8;
    float p = 0.f;
#pragma unroll
    for (int e = 0; e < 8; ++e) {
      const int k = j0 + e;
      p += bf2f(aL[BUF4 + bi*RSTR4 + k]) * __expf(trans[k*NT_ + 257]);
    }
#pragma unroll
    for (int o = 16; o; o >>= 1) p += __shfl_xor(p, o, 32);
    if ((tid & 31) == 0)
      ws[128 + bq + bi] = __logf(p) + esumL[bi]*LN2f + refL[bi];
  }
}

// ---------------------------------------------------------------------------
// llh (gold-path score) + lengths: 128 blocks x 256 threads, t-parallel.
// ---------------------------------------------------------------------------
__global__ void crf_llh(const float* __restrict__ logits, const float* __restrict__ trans,
                        const int* __restrict__ y, float* __restrict__ ws)
{
  const int b = blockIdx.x, tid = threadIdx.x;
  const int yb = b * S_;
  float part = 0.f; int cnt = 0;
  for (int t = tid; t < S_; t += 256) {
    const int yt = y[yb + t];
    const bool m = (yt >= 0);
    if (m) ++cnt;
    if (t == 0) {
      const int tag0 = m ? yt : 0;
      part += trans[TG_*NT_ + tag0];                       // T[START, y0]
      if (m) part += logits[(size_t)yb * 256 + tag0];
    } else if (m) {
      const int yp = y[yb + t - 1];                        // mask monotone => valid
      part += logits[((size_t)(yb + t)) * 256 + yt] + trans[yp*NT_ + yt];
    }
    if (m && (t + 1 == S_ || y[yb + t + 1] < 0))
      part += trans[yt*NT_ + 257];                         // T[last, END]
  }
#pragma unroll
  for (int o = 32; o; o >>= 1) { part += __shfl_xor(part, o); cnt += __shfl_xor(cnt, o); }
  __shared__ float sp[4]; __shared__ int sc[4];
  if ((tid & 63) == 0) { sp[tid >> 6] = part; sc[tid >> 6] = cnt; }
  __syncthreads();
  if (tid == 0) {
    ws[b]       = sp[0] + sp[1] + sp[2] + sp[3];
    ws[256 + b] = (float)(sc[0] + sc[1] + sc[2] + sc[3]);
  }
}

// ---------------------------------------------------------------------------
// loss = mean_b( -(llh - log_z)/len )
// ---------------------------------------------------------------------------
__global__ void crf_fin(const float* __restrict__ ws, float* __restrict__ out)
{
  const int i = threadIdx.x;  // 128
  float v = -(ws[i] - ws[128 + i]) / ws[256 + i];
#pragma unroll
  for (int o = 32; o; o >>= 1) v += __shfl_xor(v, o);
  __shared__ float s2[2];
  if ((i & 63) == 0) s2[i >> 6] = v;
  __syncthreads();
  if (i == 0) out[0] = (s2[0] + s2[1]) * (1.0f / 128.0f);
}

extern "C" void kernel_launch(void* const* d_in, const int* in_sizes, int n_in,
                              void* d_out, int out_size, void* d_ws, size_t ws_size,
                              hipStream_t stream)
{
  const float* logits = (const float*)d_in[0];
  const float* trans  = (const float*)d_in[1];
  const int*   y      = (const int*)d_in[2];
  float* ws  = (float*)d_ws;   // [0,128) llh | [128,256) log_z | [256,384) len
  float* out = (float*)d_out;

  hipLaunchKernelGGL(crf_llh,   dim3(128), dim3(256), 0, stream, logits, trans, y, ws);
  hipLaunchKernelGGL(crf_scan4, dim3(32),  dim3(512), 0, stream, logits, trans, y, ws);
  hipLaunchKernelGGL(crf_fin,   dim3(1),   dim3(128), 0, stream, ws, out);
}